// Round 1
// baseline (414.736 us; speedup 1.0000x reference)
//
#include <hip/hip_runtime.h>
#include <hip/hip_bf16.h>

#define N_STATES 25
#define N_XVALS  50          // obs in [0, 50)
#define TBL_SZ   (N_STATES * N_XVALS)
#define LOG_PROBS_PRECISION -100000.0f

// ---------------------------------------------------------------------------
// Kernel 1: build the 25x50 lookup table  T[s][x] = logprob(state s, obs x)
//   row 0: bookend  (x>0 ? -1e5 : 0)
//   rows 1..24: NB logpmf via exact integer-x identities:
//     gammaln(x+phi)-gammaln(phi) = sum_{j=0}^{x-1} log(phi+j)
//     gammaln(x+1)                = sum_{j=2}^{x}   log(j)
// ---------------------------------------------------------------------------
__global__ void build_table_kernel(const float* __restrict__ means,
                                   const float* __restrict__ phis,
                                   float* __restrict__ table) {
    int idx = blockIdx.x * blockDim.x + threadIdx.x;
    if (idx >= TBL_SZ) return;
    int s = idx / N_XVALS;
    int x = idx % N_XVALS;
    float v;
    if (s == 0) {
        v = (x > 0) ? LOG_PROBS_PRECISION : 0.0f;
    } else {
        float mu  = means[s];
        float phi = phis[s];
        float rising = 0.0f;                 // gammaln(x+phi)-gammaln(phi)
        for (int j = 0; j < x; ++j) rising += logf(phi + (float)j);
        float logfact = 0.0f;                // gammaln(x+1)
        for (int j = 2; j <= x; ++j) logfact += logf((float)j);
        float c = phi * logf(phi / (phi + mu));
        float d = logf(mu  / (phi + mu));
        v = rising - logfact + c + (float)x * d;
    }
    table[idx] = v;
}

// ---------------------------------------------------------------------------
// Kernel 2: out[s][i] = T[s][obs[i]]  — pure gather+stream-write.
// Each thread handles 4 consecutive spots (int4 load, float4 stores x25 rows).
// Table lives in LDS (5 KB).
// ---------------------------------------------------------------------------
__global__ __launch_bounds__(256) void
emit_kernel(const int* __restrict__ obs,
            const float* __restrict__ table,
            float* __restrict__ out,
            int n_spots) {
    __shared__ float t[TBL_SZ];
    for (int i = threadIdx.x; i < TBL_SZ; i += 256) t[i] = table[i];
    __syncthreads();

    int g = blockIdx.x * 256 + threadIdx.x;      // group of 4 spots
    int base = g * 4;
    if (base >= n_spots) return;

    int4 o = ((const int4*)obs)[g];
    // clamp for safety (reference guarantees 0..49)
    int x0 = min(max(o.x, 0), N_XVALS - 1);
    int x1 = min(max(o.y, 0), N_XVALS - 1);
    int x2 = min(max(o.z, 0), N_XVALS - 1);
    int x3 = min(max(o.w, 0), N_XVALS - 1);

#pragma unroll
    for (int s = 0; s < N_STATES; ++s) {
        const float* row = t + s * N_XVALS;
        float4 v;
        v.x = row[x0];
        v.y = row[x1];
        v.z = row[x2];
        v.w = row[x3];
        float4* dst = (float4*)(out + (size_t)s * (size_t)n_spots);
        dst[g] = v;
    }
}

extern "C" void kernel_launch(void* const* d_in, const int* in_sizes, int n_in,
                              void* d_out, int out_size, void* d_ws, size_t ws_size,
                              hipStream_t stream) {
    const float* means = (const float*)d_in[0];   // (25,)
    const float* phis  = (const float*)d_in[1];   // (25,)
    const int*   obs   = (const int*)d_in[2];     // (N_SPOTS,)
    float* out = (float*)d_out;                   // (25, N_SPOTS) row-major
    float* table = (float*)d_ws;                  // 1250 floats scratch

    int n_spots = in_sizes[2];

    build_table_kernel<<<(TBL_SZ + 255) / 256, 256, 0, stream>>>(means, phis, table);

    int groups = n_spots / 4;                     // n_spots = 4e6, divisible by 4
    int blocks = (groups + 255) / 256;
    emit_kernel<<<blocks, 256, 0, stream>>>(obs, table, out, n_spots);
}

// Round 3
// 414.383 us; speedup vs baseline: 1.0009x; 1.0009x over previous
//
#include <hip/hip_runtime.h>
#include <hip/hip_bf16.h>

#define N_STATES 25
#define N_XVALS  50          // obs in [0, 50)
#define TBL_SZ   (N_STATES * N_XVALS)
#define LOG_PROBS_PRECISION -100000.0f

// Native clang vector types — __builtin_nontemporal_* rejects HIP's
// class-based int4/float4 (HIP_vector_type), but accepts these.
typedef int   i32x4 __attribute__((ext_vector_type(4)));
typedef float f32x4 __attribute__((ext_vector_type(4)));

// ---------------------------------------------------------------------------
// Kernel 1: build the 25x50 lookup table  T[s][x] = logprob(state s, obs x)
//   row 0: bookend  (x>0 ? -1e5 : 0)
//   rows 1..24: NB logpmf via exact integer-x identities:
//     gammaln(x+phi)-gammaln(phi) = sum_{j=0}^{x-1} log(phi+j)
//     gammaln(x+1)                = sum_{j=2}^{x}   log(j)
// Tiny (1250 entries, 5 blocks); runs once before the streaming kernel.
// ---------------------------------------------------------------------------
__global__ void build_table_kernel(const float* __restrict__ means,
                                   const float* __restrict__ phis,
                                   float* __restrict__ table) {
    int idx = blockIdx.x * blockDim.x + threadIdx.x;
    if (idx >= TBL_SZ) return;
    int s = idx / N_XVALS;
    int x = idx % N_XVALS;
    float v;
    if (s == 0) {
        v = (x > 0) ? LOG_PROBS_PRECISION : 0.0f;
    } else {
        float mu  = means[s];
        float phi = phis[s];
        float rising = 0.0f;                 // gammaln(x+phi)-gammaln(phi)
        for (int j = 0; j < x; ++j) rising += logf(phi + (float)j);
        float logfact = 0.0f;                // gammaln(x+1)
        for (int j = 2; j <= x; ++j) logfact += logf((float)j);
        float c = phi * logf(phi / (phi + mu));
        float d = logf(mu  / (phi + mu));
        v = rising - logfact + c + (float)x * d;
    }
    table[idx] = v;
}

// ---------------------------------------------------------------------------
// Kernel 2: out[s][i] = T[s][obs[i]]  — pure gather + stream-write.
// 4 spots/thread: int4 load, 25 unit-stride float4 stores (1 KB/wave each).
// Nontemporal on both sides: output is write-once (don't thrash L2 with
// 400 MB of dead lines), obs is read-once.
// Table in LDS (5 KB); random-bank gather is ~2-way conflicts, far off the
// critical path (LDS pipe ~20k cyc/CU vs HBM ~156k cyc/CU).
// ---------------------------------------------------------------------------
__global__ __launch_bounds__(256) void
emit_kernel(const int* __restrict__ obs,
            const float* __restrict__ table,
            float* __restrict__ out,
            int n_spots) {
    __shared__ float t[TBL_SZ];
    for (int i = threadIdx.x; i < TBL_SZ; i += 256) t[i] = table[i];
    __syncthreads();

    int g = blockIdx.x * 256 + threadIdx.x;      // group of 4 spots
    if (g * 4 >= n_spots) return;

    i32x4 o = __builtin_nontemporal_load(((const i32x4*)obs) + g);
    // clamp for safety (reference guarantees 0..49)
    int x0 = min(max(o.x, 0), N_XVALS - 1);
    int x1 = min(max(o.y, 0), N_XVALS - 1);
    int x2 = min(max(o.z, 0), N_XVALS - 1);
    int x3 = min(max(o.w, 0), N_XVALS - 1);

#pragma unroll
    for (int s = 0; s < N_STATES; ++s) {
        const float* row = t + s * N_XVALS;
        f32x4 v;
        v.x = row[x0];
        v.y = row[x1];
        v.z = row[x2];
        v.w = row[x3];
        f32x4* dst = ((f32x4*)(out + (size_t)s * (size_t)n_spots)) + g;
        __builtin_nontemporal_store(v, dst);
    }
}

extern "C" void kernel_launch(void* const* d_in, const int* in_sizes, int n_in,
                              void* d_out, int out_size, void* d_ws, size_t ws_size,
                              hipStream_t stream) {
    const float* means = (const float*)d_in[0];   // (25,)
    const float* phis  = (const float*)d_in[1];   // (25,)
    const int*   obs   = (const int*)d_in[2];     // (N_SPOTS,)
    float* out = (float*)d_out;                   // (25, N_SPOTS) row-major
    float* table = (float*)d_ws;                  // 1250 floats scratch

    int n_spots = in_sizes[2];

    build_table_kernel<<<(TBL_SZ + 255) / 256, 256, 0, stream>>>(means, phis, table);

    int groups = n_spots / 4;                     // n_spots = 4e6, divisible by 4
    int blocks = (groups + 255) / 256;
    emit_kernel<<<blocks, 256, 0, stream>>>(obs, table, out, n_spots);
}